// Round 8
// baseline (428.990 us; speedup 1.0000x reference)
//
#include <hip/hip_runtime.h>
#include <hip/hip_bf16.h>
#include <hip/hip_fp16.h>
#include <hip/hip_cooperative_groups.h>
#include <stdint.h>

typedef __bf16 bf16_t;
typedef bf16_t bf16x8 __attribute__((ext_vector_type(8)));
typedef bf16_t bf16x4 __attribute__((ext_vector_type(4)));
typedef float f32x4 __attribute__((ext_vector_type(4)));

#define BM 128
#define BN 128
#define BK 64

// async global->LDS, 16B per lane. LDS dst is wave-uniform base + lane*16;
// the GLOBAL source may be arbitrary per-lane (used for the bank swizzle).
__device__ __forceinline__ void gload_lds16(const void* g, void* l) {
    __builtin_amdgcn_global_load_lds(
        (const __attribute__((address_space(1))) void*)(uintptr_t)g,
        (__attribute__((address_space(3))) void*)(uintptr_t)l,
        16, 0, 0);
}

// ---------------------------------------------------------------------------
// 128x128 body, BK=64 as TWO stacked BK=32 sub-tiles (r5: conflicts 4.3M->0).
// Each half uses the verified BK=32 swizzle: staging slot s of row r holds
// global chunk ((s-(r>>1))&3) (compensated on the per-lane global source),
// read at phys chunk ((hw+(r>>1))&3).
// EPI: 0 = plain bf16 row-major store           (gemm1 K|Q)
//      2 = f32 store / rs[row]                  (gemm3)
//      3 = exp+causal bf16 store + atomic row-sum into rs  (qk)
//      4 = bf16 transposed into Vt[b][d][s]     (gemm1 V)
// NOTE r6: per-TILE agent fences caused an L2 invalidation storm (FETCH
// 60->344 MB, 922 us). Cross-phase sync must be O(phases): r8 uses 3
// cooperative grid.sync()s instead.
// ---------------------------------------------------------------------------
template <int EPI>
__device__ __forceinline__ void gemm_body(
    bf16_t* __restrict__ As, bf16_t* __restrict__ Bs,
    const bf16_t* __restrict__ A, long lda,
    const bf16_t* __restrict__ B, long ldb,
    void* __restrict__ Cv, long ldc,
    int k0beg, int k1end, float scale, int m0, int n0,
    float* __restrict__ rs)
{
    const int tid = threadIdx.x;
    const int wid = tid >> 6, lane = tid & 63;
    const int wr = wid >> 1, wc = wid & 1;
    const int hw = lane >> 4, ln = lane & 15;

    const int row0 = tid >> 2;                       // 0..63
    const int jj = ((tid & 3) - (tid >> 3)) & 3;     // swizzle-compensated chunk
    const bf16_t* srcA0 = A + (size_t)(m0 + row0) * lda + jj * 8;
    const bf16_t* srcB0 = B + (size_t)(n0 + row0) * ldb + jj * 8;

    f32x4 acc[4][4] = {};

    for (int k0 = k0beg; k0 < k1end; k0 += BK) {
#pragma unroll
        for (int i = 0; i < 4; i++) {
            const size_t roff = (size_t)((i & 1) * 64);
            const int koff = k0 + (i >> 1) * 32;
            gload_lds16(srcA0 + roff * lda + koff, &As[i * 2048 + tid * 8]);
            gload_lds16(srcB0 + roff * ldb + koff, &Bs[i * 2048 + tid * 8]);
        }
        __syncthreads();

#pragma unroll
        for (int h = 0; h < 2; h++) {
            bf16x8 af[4], bfr[4];
#pragma unroll
            for (int t = 0; t < 4; t++) {
                const int r  = wr * 64 + t * 16 + ln;
                const int rb = wc * 64 + t * 16 + ln;
                af[t]  = *(const bf16x8*)&As[h * 4096 + r  * 32 + (((hw + (r  >> 1)) & 3) * 8)];
                bfr[t] = *(const bf16x8*)&Bs[h * 4096 + rb * 32 + (((hw + (rb >> 1)) & 3) * 8)];
            }
#pragma unroll
            for (int ti = 0; ti < 4; ti++)
#pragma unroll
                for (int tj = 0; tj < 4; tj++)
                    acc[ti][tj] = __builtin_amdgcn_mfma_f32_16x16x32_bf16(
                        af[ti], bfr[tj], acc[ti][tj], 0, 0, 0);
        }
        __syncthreads();
    }

    // epilogue: C/D layout col=lane&15, row=(lane>>4)*4+reg (m89-verified)
#pragma unroll
    for (int ti = 0; ti < 4; ti++) {
        const int rbase = m0 + wr * 64 + ti * 16 + hw * 4;
        f32x4 inv4;
        if (EPI == 2) {
            const float4 r4 = *(const float4*)&rs[rbase];
            inv4[0] = 1.0f / r4.x; inv4[1] = 1.0f / r4.y;
            inv4[2] = 1.0f / r4.z; inv4[3] = 1.0f / r4.w;
        }
        float part[4] = {0.f, 0.f, 0.f, 0.f};
#pragma unroll
        for (int tj = 0; tj < 4; tj++) {
            const int col = n0 + wc * 64 + tj * 16 + ln;
            if (EPI == 4) {
                // transposed bf16: 4 consecutive rows -> 8B contiguous in Vt
                const int bb = rbase >> 11;
                const int s  = rbase & 2047;
                const int d  = col - 2048;
                bf16x4 o;
#pragma unroll
                for (int rg = 0; rg < 4; rg++) o[rg] = (bf16_t)acc[ti][tj][rg];
                *(bf16x4*)&((bf16_t*)Cv)[(size_t)bb * 2097152 + (size_t)d * 2048 + s] = o;
            } else {
#pragma unroll
                for (int rg = 0; rg < 4; rg++) {
                    const size_t idx = (size_t)(rbase + rg) * ldc + col;
                    if (EPI == 0) {
                        ((bf16_t*)Cv)[idx] = (bf16_t)acc[ti][tj][rg];
                    } else if (EPI == 2) {
                        ((float*)Cv)[idx] = acc[ti][tj][rg] * inv4[rg];
                    } else {  // EPI 3: exp + causal mask + row-sum
                        const float e = (col <= rbase + rg)
                                      ? __expf(acc[ti][tj][rg] * scale) : 0.0f;
                        part[rg] += e;
                        ((bf16_t*)Cv)[idx] = (bf16_t)e;
                    }
                }
            }
        }
        if (EPI == 3) {
#pragma unroll
            for (int rg = 0; rg < 4; rg++) {
                float p = part[rg];
                p += __shfl_xor(p, 1, 64);
                p += __shfl_xor(p, 2, 64);
                p += __shfl_xor(p, 4, 64);
                p += __shfl_xor(p, 8, 64);
                if (ln == 0) atomicAdd(&rs[rbase + rg], p);
            }
        }
    }
}

// ------------------------- shared tile-mapping helpers ---------------------
__device__ __forceinline__ void kq_tile(int g, int& m0, int& n0) {
    // 1024 tiles = 64 mblk x 16 nblk; XCD-pinned: xcd owns mblk [8x,8x+8),
    // per-phase footprint 2+2 MB = one XCD L2.
    const int xcd = g & 7;
    const int j   = g >> 3;
    const int p   = j >> 6;                // 0..1
    const int w   = j & 63;
    m0 = (xcd * 8 + (w >> 3)) * BM;
    n0 = (p * 8 + (w & 7)) * BN;
}

__device__ __forceinline__ void qk_tile(int q, int& b, int& my, int& nx) {
    b = q & 3;
    int rem = q >> 2;                      // 0..135
    my = 15; nx = 0;
#pragma unroll
    for (int m = 15; m >= 0; --m) {        // heavy strips first
        if (rem < m + 1) { my = m; nx = rem; break; }
        rem -= m + 1;
    }
}

// ---------------------------------------------------------------------------
// COOP mega-kernel (r8): 4 phases, 3 grid.sync()s (O(phases) fences — the
// fix for r6's O(tiles) L2 storm). All phases grid-stride so any grid size
// is correct; launch clamps grid to the occupancy query.
// ---------------------------------------------------------------------------
__global__ __launch_bounds__(256, 4) void coop_mega(
    const float* __restrict__ x,
    const float* __restrict__ Wk, const float* __restrict__ Wq,
    const float* __restrict__ Wv,
    bf16_t* __restrict__ xb, bf16_t* __restrict__ Wb,
    bf16_t* __restrict__ QKVb, bf16_t* __restrict__ Vt,
    bf16_t* __restrict__ E, float* __restrict__ rowsum,
    float* __restrict__ out)
{
    cooperative_groups::grid_group gg = cooperative_groups::this_grid();
    __shared__ __align__(16) bf16_t As[BM * BK];
    __shared__ __align__(16) bf16_t Bs[BN * BK];
    const int tid = threadIdx.x;
    const int nb = gridDim.x;

    // ---- phase 0: cast x,W -> bf16; zero rowsum
    for (int u = blockIdx.x; u < 11272; u += nb) {
        if (u >= 11264) {
            const size_t i = ((size_t)(u - 11264) * 256 + tid) * 4;
            *(float4*)(rowsum + i) = make_float4(0.f, 0.f, 0.f, 0.f);
            continue;
        }
        const float* src;
        bf16_t* dst;
        if (u < 8192) {
            const size_t i = ((size_t)u * 256 + tid) * 4;
            src = x + i; dst = xb + i;
        } else {
            const size_t j = ((size_t)(u - 8192) * 256 + tid) * 4;
            dst = Wb + j;
            if (j < (size_t)1048576)      src = Wk + j;
            else if (j < (size_t)2097152) src = Wq + (j - 1048576);
            else                          src = Wv + (j - 2097152);
        }
        const float4 v = *(const float4*)src;
        bf16x4 o;
        o.x = (bf16_t)v.x; o.y = (bf16_t)v.y;
        o.z = (bf16_t)v.z; o.w = (bf16_t)v.w;
        *(bf16x4*)dst = o;
    }
    gg.sync();

    // ---- phase 1: K|Q projection (1024 x 128^2 tiles)
    for (int t = blockIdx.x; t < 1024; t += nb) {
        int m0, n0;
        kq_tile(t, m0, n0);
        gemm_body<0>(As, Bs, xb, 1024, Wb, 1024, QKVb, 2048,
                     0, 1024, 1.0f, m0, n0, nullptr);
    }
    gg.sync();

    // ---- phase 2: V projection (512) + causal exp(QK^T) (544)
    for (int t = blockIdx.x; t < 1056; t += nb) {
        if (t < 512) {
            const int xcd = t & 7;
            const int j   = t >> 3;
            const int mblk = xcd * 8 + (j >> 3);
            const int nblk = j & 7;
            gemm_body<4>(As, Bs, xb, 1024, Wb, 1024, Vt, 2048,
                         0, 1024, 1.0f, mblk * BM, 2048 + nblk * BN, nullptr);
        } else {
            int b, my, nx;
            qk_tile(t - 512, b, my, nx);
            const bf16_t* base = QKVb + (size_t)b * (2048L * 2048);
            gemm_body<3>(As, Bs,
                         base + 1024, 2048,    // Q
                         base, 2048,           // K
                         E + (size_t)b * (2048L * 2048), 2048,
                         0, 1024, 0.03125f, my * BM, nx * BN,
                         rowsum + b * 2048);
        }
    }
    gg.sync();

    // ---- phase 3: out = (E Vt^T)/rowsum, tri-K
    for (int t = blockIdx.x; t < 512; t += nb) {
        const int strip = (t < 256) ? (15 - (t >> 5)) : ((t - 256) >> 5);
        const int nx = (t >> 2) & 7;
        const int b = t & 3;
        const int m0 = strip * BM;
        gemm_body<2>(As, Bs,
                     E + (size_t)b * (2048L * 2048), 2048,
                     Vt + (size_t)b * (1024L * 2048), 2048,
                     out + (size_t)b * (2048L * 1024), 1024,
                     0, m0 + BM, 1.0f, m0, nx * BN,
                     rowsum + b * 2048);
    }
}

// ======================= fallback path (4 dispatches) ======================
__global__ __launch_bounds__(256) void cast_all(
    const float* __restrict__ x,
    const float* __restrict__ Wk, const float* __restrict__ Wq,
    const float* __restrict__ Wv,
    bf16_t* __restrict__ xb, bf16_t* __restrict__ Wb,
    float* __restrict__ rowsum)
{
    const int blk = blockIdx.x;
    if (blk >= 11264) {
        const size_t i = ((size_t)(blk - 11264) * 256 + threadIdx.x) * 4;
        *(float4*)(rowsum + i) = make_float4(0.f, 0.f, 0.f, 0.f);
        return;
    }
    const float* src;
    bf16_t* dst;
    if (blk < 8192) {
        const size_t i = ((size_t)blk * 256 + threadIdx.x) * 4;
        src = x + i;
        dst = xb + i;
    } else {
        const size_t j = ((size_t)(blk - 8192) * 256 + threadIdx.x) * 4;
        dst = Wb + j;
        if (j < (size_t)1048576)      src = Wk + j;
        else if (j < (size_t)2097152) src = Wq + (j - 1048576);
        else                          src = Wv + (j - 2097152);
    }
    const float4 v = *(const float4*)src;
    bf16x4 o;
    o.x = (bf16_t)v.x; o.y = (bf16_t)v.y; o.z = (bf16_t)v.z; o.w = (bf16_t)v.w;
    *(bf16x4*)dst = o;
}

__global__ __launch_bounds__(256) void gemm1_kq128(
    const bf16_t* __restrict__ xb, const bf16_t* __restrict__ Wb,
    bf16_t* __restrict__ QKVb)
{
    __shared__ __align__(16) bf16_t As[BM * BK];
    __shared__ __align__(16) bf16_t Bs[BN * BK];
    int m0, n0;
    kq_tile(blockIdx.x, m0, n0);
    gemm_body<0>(As, Bs, xb, 1024, Wb, 1024, QKVb, 2048,
                 0, 1024, 1.0f, m0, n0, nullptr);
}

__global__ __launch_bounds__(256) void vqk_fused(
    const bf16_t* __restrict__ xb, const bf16_t* __restrict__ Wb,
    bf16_t* __restrict__ Vt,
    const bf16_t* __restrict__ QKVb, bf16_t* __restrict__ E,
    float* __restrict__ rowsum)
{
    __shared__ __align__(16) bf16_t As[BM * BK];
    __shared__ __align__(16) bf16_t Bs[BN * BK];
    const int id = blockIdx.x;
    if (id < 512) {
        const int xcd = id & 7;
        const int j   = id >> 3;
        const int mblk = xcd * 8 + (j >> 3);
        const int nblk = j & 7;
        gemm_body<4>(As, Bs, xb, 1024, Wb, 1024, Vt, 2048,
                     0, 1024, 1.0f, mblk * BM, 2048 + nblk * BN, nullptr);
    } else {
        int b, my, nx;
        qk_tile(id - 512, b, my, nx);
        const bf16_t* base = QKVb + (size_t)b * (2048L * 2048);
        gemm_body<3>(As, Bs,
                     base + 1024, 2048,
                     base, 2048,
                     E + (size_t)b * (2048L * 2048), 2048,
                     0, 1024, 0.03125f, my * BM, nx * BN,
                     rowsum + b * 2048);
    }
}

__global__ __launch_bounds__(256) void gemm1_v(
    const bf16_t* __restrict__ xb, const bf16_t* __restrict__ Wb,
    bf16_t* __restrict__ Vt)
{
    __shared__ __align__(16) bf16_t As[BM * BK];
    __shared__ __align__(16) bf16_t Bs[BN * BK];
    const int lin = blockIdx.x;
    const int xcd = lin & 7;
    const int j   = lin >> 3;
    const int mblk = xcd * 8 + (j >> 3);
    const int nblk = j & 7;
    gemm_body<4>(As, Bs, xb, 1024, Wb, 1024, Vt, 2048,
                 0, 1024, 1.0f, mblk * BM, 2048 + nblk * BN, nullptr);
}

__global__ __launch_bounds__(256) void qk_gemm(
    const bf16_t* __restrict__ QKVb, bf16_t* __restrict__ E,
    float* __restrict__ rowsum)
{
    __shared__ __align__(16) bf16_t As[BM * BK];
    __shared__ __align__(16) bf16_t Bs[BN * BK];
    int b, my, nx;
    qk_tile(blockIdx.x, b, my, nx);
    const bf16_t* base = QKVb + (size_t)b * (2048L * 2048);
    gemm_body<3>(As, Bs,
                 base + 1024, 2048,
                 base, 2048,
                 E + (size_t)b * (2048L * 2048), 2048,
                 0, 1024, 0.03125f, my * BM, nx * BN,
                 rowsum + b * 2048);
}

__global__ __launch_bounds__(256) void gemm3_pv(
    const bf16_t* __restrict__ E, const bf16_t* __restrict__ Vt,
    const float* __restrict__ rowsum, float* __restrict__ out)
{
    __shared__ __align__(16) bf16_t As[BM * BK];
    __shared__ __align__(16) bf16_t Bs[BN * BK];
    const int id = blockIdx.x;
    const int strip = (id < 256) ? (15 - (id >> 5)) : ((id - 256) >> 5);
    const int nx = (id >> 2) & 7;
    const int b = id & 3;
    const int m0 = strip * BM;
    gemm_body<2>(As, Bs,
                 E + (size_t)b * (2048L * 2048), 2048,
                 Vt + (size_t)b * (1024L * 2048), 2048,
                 out + (size_t)b * (2048L * 1024), 1024,
                 0, m0 + BM, 1.0f, m0, nx * BN,
                 (float*)rowsum + b * 2048);
}

// ---------------------------------------------------------------------------
extern "C" void kernel_launch(void* const* d_in, const int* in_sizes, int n_in,
                              void* d_out, int out_size, void* d_ws, size_t ws_size,
                              hipStream_t stream)
{
    const float* x  = (const float*)d_in[0];
    const float* Wk = (const float*)d_in[1];
    const float* Wq = (const float*)d_in[2];
    const float* Wv = (const float*)d_in[3];
    char* ws = (char*)d_ws;

    // ws layout (big path, >=107 MB):
    //   [0,32)    QKVb  [32,48) Vt  [48,64) xb  [64,70) Wb
    //   [72,105.6) E (non-aliased)  [106,...) rowsum f32 4x2048
    // small-ws fallback: E aliases xb+Wb at [48,80), rowsum at [80,...).
    bf16_t* QKVb = (bf16_t*)(ws);
    bf16_t* Vt   = (bf16_t*)(ws + ((size_t)32 << 20));
    bf16_t* xb   = (bf16_t*)(ws + ((size_t)48 << 20));
    bf16_t* Wb   = (bf16_t*)(ws + ((size_t)64 << 20));
    const bool big = ws_size >= ((size_t)107 << 20);
    bf16_t* E      = (bf16_t*)(ws + ((size_t)(big ? 72 : 48) << 20));
    float*  rowsum = (float*)(ws + ((size_t)(big ? 106 : 80) << 20));
    float*  out    = (float*)d_out;

    bool done = false;
    if (big) {
        int occ = 0;
        if (hipOccupancyMaxActiveBlocksPerMultiprocessor(&occ, coop_mega, 256, 0)
                == hipSuccess && occ > 0) {
            int grid = occ * 256;          // 256 CUs on MI355X
            if (grid > 1024) grid = 1024;
            void* args[] = {
                (void*)&x, (void*)&Wk, (void*)&Wq, (void*)&Wv,
                (void*)&xb, (void*)&Wb, (void*)&QKVb, (void*)&Vt,
                (void*)&E, (void*)&rowsum, (void*)&out };
            if (hipLaunchCooperativeKernel(coop_mega, dim3(grid), dim3(256),
                                           args, 0, stream) == hipSuccess)
                done = true;
        }
    }

    if (!done) {
        cast_all<<<11272, 256, 0, stream>>>(x, Wk, Wq, Wv, xb, Wb, rowsum);
        gemm1_kq128<<<1024, 256, 0, stream>>>(xb, Wb, QKVb);
        if (big) {
            vqk_fused<<<1056, 256, 0, stream>>>(xb, Wb, Vt, QKVb, E, rowsum);
        } else {
            gemm1_v<<<512, 256, 0, stream>>>(xb, Wb, Vt);
            qk_gemm<<<544, 256, 0, stream>>>(QKVb, E, rowsum);
        }
        gemm3_pv<<<512, 256, 0, stream>>>(E, Vt, rowsum, out);
    }
}

// Round 9
// 233.717 us; speedup vs baseline: 1.8355x; 1.8355x over previous
//
#include <hip/hip_runtime.h>
#include <hip/hip_bf16.h>
#include <hip/hip_fp16.h>
#include <hip/hip_cooperative_groups.h>
#include <stdint.h>

typedef __bf16 bf16_t;
typedef bf16_t bf16x8 __attribute__((ext_vector_type(8)));
typedef bf16_t bf16x4 __attribute__((ext_vector_type(4)));
typedef float f32x4 __attribute__((ext_vector_type(4)));

#define BM 128
#define BN 128
#define BK 64

// async global->LDS, 16B per lane. LDS dst is wave-uniform base + lane*16;
// the GLOBAL source may be arbitrary per-lane (used for the bank swizzle).
__device__ __forceinline__ void gload_lds16(const void* g, void* l) {
    __builtin_amdgcn_global_load_lds(
        (const __attribute__((address_space(1))) void*)(uintptr_t)g,
        (__attribute__((address_space(3))) void*)(uintptr_t)l,
        16, 0, 0);
}

// ---------------------------------------------------------------------------
// 128x128 body, BK=64 as TWO stacked BK=32 sub-tiles (r5: conflicts 4.3M->0).
// EPI: 0 = plain bf16 row-major store           (gemm1 K|Q)
//      2 = f32 store / rs[row]                  (gemm3)
//      3 = exp+causal bf16 store + atomic row-sum into rs  (qk)
//      4 = bf16 transposed into Vt[b][d][s]     (gemm1 V)
// HISTORY: r6 per-tile agent fences -> L2 storm (FETCH 344 MB, 922 us).
// r8 coop with __launch_bounds__(256,4) -> VGPR capped at 64, body needs
// ~90+ -> scratch spill storm (FETCH 131 MB, MfmaUtil 6%, 560 us).
// r9: coop retained, NO min-waves cap (single-variable fix of r8).
// ---------------------------------------------------------------------------
template <int EPI>
__device__ __forceinline__ void gemm_body(
    bf16_t* __restrict__ As, bf16_t* __restrict__ Bs,
    const bf16_t* __restrict__ A, long lda,
    const bf16_t* __restrict__ B, long ldb,
    void* __restrict__ Cv, long ldc,
    int k0beg, int k1end, float scale, int m0, int n0,
    float* __restrict__ rs)
{
    const int tid = threadIdx.x;
    const int wid = tid >> 6, lane = tid & 63;
    const int wr = wid >> 1, wc = wid & 1;
    const int hw = lane >> 4, ln = lane & 15;

    const int row0 = tid >> 2;                       // 0..63
    const int jj = ((tid & 3) - (tid >> 3)) & 3;     // swizzle-compensated chunk
    const bf16_t* srcA0 = A + (size_t)(m0 + row0) * lda + jj * 8;
    const bf16_t* srcB0 = B + (size_t)(n0 + row0) * ldb + jj * 8;

    f32x4 acc[4][4] = {};

    for (int k0 = k0beg; k0 < k1end; k0 += BK) {
#pragma unroll
        for (int i = 0; i < 4; i++) {
            const size_t roff = (size_t)((i & 1) * 64);
            const int koff = k0 + (i >> 1) * 32;
            gload_lds16(srcA0 + roff * lda + koff, &As[i * 2048 + tid * 8]);
            gload_lds16(srcB0 + roff * ldb + koff, &Bs[i * 2048 + tid * 8]);
        }
        __syncthreads();

#pragma unroll
        for (int h = 0; h < 2; h++) {
            bf16x8 af[4], bfr[4];
#pragma unroll
            for (int t = 0; t < 4; t++) {
                const int r  = wr * 64 + t * 16 + ln;
                const int rb = wc * 64 + t * 16 + ln;
                af[t]  = *(const bf16x8*)&As[h * 4096 + r  * 32 + (((hw + (r  >> 1)) & 3) * 8)];
                bfr[t] = *(const bf16x8*)&Bs[h * 4096 + rb * 32 + (((hw + (rb >> 1)) & 3) * 8)];
            }
#pragma unroll
            for (int ti = 0; ti < 4; ti++)
#pragma unroll
                for (int tj = 0; tj < 4; tj++)
                    acc[ti][tj] = __builtin_amdgcn_mfma_f32_16x16x32_bf16(
                        af[ti], bfr[tj], acc[ti][tj], 0, 0, 0);
        }
        __syncthreads();
    }

    // epilogue: C/D layout col=lane&15, row=(lane>>4)*4+reg (m89-verified)
#pragma unroll
    for (int ti = 0; ti < 4; ti++) {
        const int rbase = m0 + wr * 64 + ti * 16 + hw * 4;
        f32x4 inv4;
        if (EPI == 2) {
            const float4 r4 = *(const float4*)&rs[rbase];
            inv4[0] = 1.0f / r4.x; inv4[1] = 1.0f / r4.y;
            inv4[2] = 1.0f / r4.z; inv4[3] = 1.0f / r4.w;
        }
        float part[4] = {0.f, 0.f, 0.f, 0.f};
#pragma unroll
        for (int tj = 0; tj < 4; tj++) {
            const int col = n0 + wc * 64 + tj * 16 + ln;
            if (EPI == 4) {
                // transposed bf16: 4 consecutive rows -> 8B contiguous in Vt
                const int bb = rbase >> 11;
                const int s  = rbase & 2047;
                const int d  = col - 2048;
                bf16x4 o;
#pragma unroll
                for (int rg = 0; rg < 4; rg++) o[rg] = (bf16_t)acc[ti][tj][rg];
                *(bf16x4*)&((bf16_t*)Cv)[(size_t)bb * 2097152 + (size_t)d * 2048 + s] = o;
            } else {
#pragma unroll
                for (int rg = 0; rg < 4; rg++) {
                    const size_t idx = (size_t)(rbase + rg) * ldc + col;
                    if (EPI == 0) {
                        ((bf16_t*)Cv)[idx] = (bf16_t)acc[ti][tj][rg];
                    } else if (EPI == 2) {
                        ((float*)Cv)[idx] = acc[ti][tj][rg] * inv4[rg];
                    } else {  // EPI 3: exp + causal mask + row-sum
                        const float e = (col <= rbase + rg)
                                      ? __expf(acc[ti][tj][rg] * scale) : 0.0f;
                        part[rg] += e;
                        ((bf16_t*)Cv)[idx] = (bf16_t)e;
                    }
                }
            }
        }
        if (EPI == 3) {
#pragma unroll
            for (int rg = 0; rg < 4; rg++) {
                float p = part[rg];
                p += __shfl_xor(p, 1, 64);
                p += __shfl_xor(p, 2, 64);
                p += __shfl_xor(p, 4, 64);
                p += __shfl_xor(p, 8, 64);
                if (ln == 0) atomicAdd(&rs[rbase + rg], p);
            }
        }
    }
}

// ------------------------- shared tile-mapping helpers ---------------------
__device__ __forceinline__ void kq_tile(int g, int& m0, int& n0) {
    const int xcd = g & 7;
    const int j   = g >> 3;
    const int p   = j >> 6;                // 0..1
    const int w   = j & 63;
    m0 = (xcd * 8 + (w >> 3)) * BM;
    n0 = (p * 8 + (w & 7)) * BN;
}

__device__ __forceinline__ void qk_tile(int q, int& b, int& my, int& nx) {
    b = q & 3;
    int rem = q >> 2;                      // 0..135
    my = 15; nx = 0;
#pragma unroll
    for (int m = 15; m >= 0; --m) {        // heavy strips first
        if (rem < m + 1) { my = m; nx = rem; break; }
        rem -= m + 1;
    }
}

// ---------------------------------------------------------------------------
// COOP mega-kernel (r9): 4 phases, 3 grid.sync()s. NO launch-bounds min-wave
// cap (r8's VGPR=64 spill storm). Grid sized by occupancy query; all phases
// grid-stride so any grid size is correct.
// ---------------------------------------------------------------------------
__global__ __launch_bounds__(256) void coop_mega(
    const float* __restrict__ x,
    const float* __restrict__ Wk, const float* __restrict__ Wq,
    const float* __restrict__ Wv,
    bf16_t* __restrict__ xb, bf16_t* __restrict__ Wb,
    bf16_t* __restrict__ QKVb, bf16_t* __restrict__ Vt,
    bf16_t* __restrict__ E, float* __restrict__ rowsum,
    float* __restrict__ out)
{
    cooperative_groups::grid_group gg = cooperative_groups::this_grid();
    __shared__ __align__(16) bf16_t As[BM * BK];
    __shared__ __align__(16) bf16_t Bs[BN * BK];
    const int tid = threadIdx.x;
    const int nb = gridDim.x;

    // ---- phase 0: cast x,W -> bf16; zero rowsum
    for (int u = blockIdx.x; u < 11272; u += nb) {
        if (u >= 11264) {
            const size_t i = ((size_t)(u - 11264) * 256 + tid) * 4;
            *(float4*)(rowsum + i) = make_float4(0.f, 0.f, 0.f, 0.f);
            continue;
        }
        const float* src;
        bf16_t* dst;
        if (u < 8192) {
            const size_t i = ((size_t)u * 256 + tid) * 4;
            src = x + i; dst = xb + i;
        } else {
            const size_t j = ((size_t)(u - 8192) * 256 + tid) * 4;
            dst = Wb + j;
            if (j < (size_t)1048576)      src = Wk + j;
            else if (j < (size_t)2097152) src = Wq + (j - 1048576);
            else                          src = Wv + (j - 2097152);
        }
        const float4 v = *(const float4*)src;
        bf16x4 o;
        o.x = (bf16_t)v.x; o.y = (bf16_t)v.y;
        o.z = (bf16_t)v.z; o.w = (bf16_t)v.w;
        *(bf16x4*)dst = o;
    }
    gg.sync();

    // ---- phase 1: K|Q projection (1024 x 128^2 tiles)
    for (int t = blockIdx.x; t < 1024; t += nb) {
        int m0, n0;
        kq_tile(t, m0, n0);
        gemm_body<0>(As, Bs, xb, 1024, Wb, 1024, QKVb, 2048,
                     0, 1024, 1.0f, m0, n0, nullptr);
    }
    gg.sync();

    // ---- phase 2: V projection (512) + causal exp(QK^T) (544)
    for (int t = blockIdx.x; t < 1056; t += nb) {
        if (t < 512) {
            const int xcd = t & 7;
            const int j   = t >> 3;
            const int mblk = xcd * 8 + (j >> 3);
            const int nblk = j & 7;
            gemm_body<4>(As, Bs, xb, 1024, Wb, 1024, Vt, 2048,
                         0, 1024, 1.0f, mblk * BM, 2048 + nblk * BN, nullptr);
        } else {
            int b, my, nx;
            qk_tile(t - 512, b, my, nx);
            const bf16_t* base = QKVb + (size_t)b * (2048L * 2048);
            gemm_body<3>(As, Bs,
                         base + 1024, 2048,    // Q
                         base, 2048,           // K
                         E + (size_t)b * (2048L * 2048), 2048,
                         0, 1024, 0.03125f, my * BM, nx * BN,
                         rowsum + b * 2048);
        }
    }
    gg.sync();

    // ---- phase 3: out = (E Vt^T)/rowsum, tri-K
    for (int t = blockIdx.x; t < 512; t += nb) {
        const int strip = (t < 256) ? (15 - (t >> 5)) : ((t - 256) >> 5);
        const int nx = (t >> 2) & 7;
        const int b = t & 3;
        const int m0 = strip * BM;
        gemm_body<2>(As, Bs,
                     E + (size_t)b * (2048L * 2048), 2048,
                     Vt + (size_t)b * (1024L * 2048), 2048,
                     out + (size_t)b * (2048L * 1024), 1024,
                     0, m0 + BM, 1.0f, m0, nx * BN,
                     rowsum + b * 2048);
    }
}

// ======================= fallback path (4 dispatches) ======================
__global__ __launch_bounds__(256) void cast_all(
    const float* __restrict__ x,
    const float* __restrict__ Wk, const float* __restrict__ Wq,
    const float* __restrict__ Wv,
    bf16_t* __restrict__ xb, bf16_t* __restrict__ Wb,
    float* __restrict__ rowsum)
{
    const int blk = blockIdx.x;
    if (blk >= 11264) {
        const size_t i = ((size_t)(blk - 11264) * 256 + threadIdx.x) * 4;
        *(float4*)(rowsum + i) = make_float4(0.f, 0.f, 0.f, 0.f);
        return;
    }
    const float* src;
    bf16_t* dst;
    if (blk < 8192) {
        const size_t i = ((size_t)blk * 256 + threadIdx.x) * 4;
        src = x + i;
        dst = xb + i;
    } else {
        const size_t j = ((size_t)(blk - 8192) * 256 + threadIdx.x) * 4;
        dst = Wb + j;
        if (j < (size_t)1048576)      src = Wk + j;
        else if (j < (size_t)2097152) src = Wq + (j - 1048576);
        else                          src = Wv + (j - 2097152);
    }
    const float4 v = *(const float4*)src;
    bf16x4 o;
    o.x = (bf16_t)v.x; o.y = (bf16_t)v.y; o.z = (bf16_t)v.z; o.w = (bf16_t)v.w;
    *(bf16x4*)dst = o;
}

__global__ __launch_bounds__(256) void gemm1_kq128(
    const bf16_t* __restrict__ xb, const bf16_t* __restrict__ Wb,
    bf16_t* __restrict__ QKVb)
{
    __shared__ __align__(16) bf16_t As[BM * BK];
    __shared__ __align__(16) bf16_t Bs[BN * BK];
    int m0, n0;
    kq_tile(blockIdx.x, m0, n0);
    gemm_body<0>(As, Bs, xb, 1024, Wb, 1024, QKVb, 2048,
                 0, 1024, 1.0f, m0, n0, nullptr);
}

__global__ __launch_bounds__(256) void vqk_fused(
    const bf16_t* __restrict__ xb, const bf16_t* __restrict__ Wb,
    bf16_t* __restrict__ Vt,
    const bf16_t* __restrict__ QKVb, bf16_t* __restrict__ E,
    float* __restrict__ rowsum)
{
    __shared__ __align__(16) bf16_t As[BM * BK];
    __shared__ __align__(16) bf16_t Bs[BN * BK];
    const int id = blockIdx.x;
    if (id < 512) {
        const int xcd = id & 7;
        const int j   = id >> 3;
        const int mblk = xcd * 8 + (j >> 3);
        const int nblk = j & 7;
        gemm_body<4>(As, Bs, xb, 1024, Wb, 1024, Vt, 2048,
                     0, 1024, 1.0f, mblk * BM, 2048 + nblk * BN, nullptr);
    } else {
        int b, my, nx;
        qk_tile(id - 512, b, my, nx);
        const bf16_t* base = QKVb + (size_t)b * (2048L * 2048);
        gemm_body<3>(As, Bs,
                     base + 1024, 2048,
                     base, 2048,
                     E + (size_t)b * (2048L * 2048), 2048,
                     0, 1024, 0.03125f, my * BM, nx * BN,
                     rowsum + b * 2048);
    }
}

__global__ __launch_bounds__(256) void gemm1_v(
    const bf16_t* __restrict__ xb, const bf16_t* __restrict__ Wb,
    bf16_t* __restrict__ Vt)
{
    __shared__ __align__(16) bf16_t As[BM * BK];
    __shared__ __align__(16) bf16_t Bs[BN * BK];
    const int lin = blockIdx.x;
    const int xcd = lin & 7;
    const int j   = lin >> 3;
    const int mblk = xcd * 8 + (j >> 3);
    const int nblk = j & 7;
    gemm_body<4>(As, Bs, xb, 1024, Wb, 1024, Vt, 2048,
                 0, 1024, 1.0f, mblk * BM, 2048 + nblk * BN, nullptr);
}

__global__ __launch_bounds__(256) void qk_gemm(
    const bf16_t* __restrict__ QKVb, bf16_t* __restrict__ E,
    float* __restrict__ rowsum)
{
    __shared__ __align__(16) bf16_t As[BM * BK];
    __shared__ __align__(16) bf16_t Bs[BN * BK];
    int b, my, nx;
    qk_tile(blockIdx.x, b, my, nx);
    const bf16_t* base = QKVb + (size_t)b * (2048L * 2048);
    gemm_body<3>(As, Bs,
                 base + 1024, 2048,
                 base, 2048,
                 E + (size_t)b * (2048L * 2048), 2048,
                 0, 1024, 0.03125f, my * BM, nx * BN,
                 rowsum + b * 2048);
}

__global__ __launch_bounds__(256) void gemm3_pv(
    const bf16_t* __restrict__ E, const bf16_t* __restrict__ Vt,
    const float* __restrict__ rowsum, float* __restrict__ out)
{
    __shared__ __align__(16) bf16_t As[BM * BK];
    __shared__ __align__(16) bf16_t Bs[BN * BK];
    const int id = blockIdx.x;
    const int strip = (id < 256) ? (15 - (id >> 5)) : ((id - 256) >> 5);
    const int nx = (id >> 2) & 7;
    const int b = id & 3;
    const int m0 = strip * BM;
    gemm_body<2>(As, Bs,
                 E + (size_t)b * (2048L * 2048), 2048,
                 Vt + (size_t)b * (1024L * 2048), 2048,
                 out + (size_t)b * (2048L * 1024), 1024,
                 0, m0 + BM, 1.0f, m0, nx * BN,
                 (float*)rowsum + b * 2048);
}

// ---------------------------------------------------------------------------
extern "C" void kernel_launch(void* const* d_in, const int* in_sizes, int n_in,
                              void* d_out, int out_size, void* d_ws, size_t ws_size,
                              hipStream_t stream)
{
    const float* x  = (const float*)d_in[0];
    const float* Wk = (const float*)d_in[1];
    const float* Wq = (const float*)d_in[2];
    const float* Wv = (const float*)d_in[3];
    char* ws = (char*)d_ws;

    // ws layout (big path, >=107 MB):
    //   [0,32)    QKVb  [32,48) Vt  [48,64) xb  [64,70) Wb
    //   [72,105.6) E (non-aliased)  [106,...) rowsum f32 4x2048
    // small-ws fallback: E aliases xb+Wb at [48,80), rowsum at [80,...).
    bf16_t* QKVb = (bf16_t*)(ws);
    bf16_t* Vt   = (bf16_t*)(ws + ((size_t)32 << 20));
    bf16_t* xb   = (bf16_t*)(ws + ((size_t)48 << 20));
    bf16_t* Wb   = (bf16_t*)(ws + ((size_t)64 << 20));
    const bool big = ws_size >= ((size_t)107 << 20);
    bf16_t* E      = (bf16_t*)(ws + ((size_t)(big ? 72 : 48) << 20));
    float*  rowsum = (float*)(ws + ((size_t)(big ? 106 : 80) << 20));
    float*  out    = (float*)d_out;

    bool done = false;
    if (big) {
        int occ = 0;
        if (hipOccupancyMaxActiveBlocksPerMultiprocessor(&occ, coop_mega, 256, 0)
                == hipSuccess && occ > 0) {
            int grid = occ * 256;          // 256 CUs on MI355X
            if (grid > 1024) grid = 1024;
            void* args[] = {
                (void*)&x, (void*)&Wk, (void*)&Wq, (void*)&Wv,
                (void*)&xb, (void*)&Wb, (void*)&QKVb, (void*)&Vt,
                (void*)&E, (void*)&rowsum, (void*)&out };
            if (hipLaunchCooperativeKernel(coop_mega, dim3(grid), dim3(256),
                                           args, 0, stream) == hipSuccess)
                done = true;
        }
    }

    if (!done) {
        cast_all<<<11272, 256, 0, stream>>>(x, Wk, Wq, Wv, xb, Wb, rowsum);
        gemm1_kq128<<<1024, 256, 0, stream>>>(xb, Wb, QKVb);
        if (big) {
            vqk_fused<<<1056, 256, 0, stream>>>(xb, Wb, Vt, QKVb, E, rowsum);
        } else {
            gemm1_v<<<512, 256, 0, stream>>>(xb, Wb, Vt);
            qk_gemm<<<544, 256, 0, stream>>>(QKVb, E, rowsum);
        }
        gemm3_pv<<<512, 256, 0, stream>>>(E, Vt, rowsum, out);
    }
}